// Round 4
// baseline (3220.545 us; speedup 1.0000x reference)
//
#include <hip/hip_runtime.h>

// ---------- types ----------
typedef __bf16 bft;
typedef bft bf16x8 __attribute__((ext_vector_type(8)));
typedef bft bf16x4 __attribute__((ext_vector_type(4)));
typedef bft bf16x2 __attribute__((ext_vector_type(2)));
typedef float f32x4 __attribute__((ext_vector_type(4)));
typedef unsigned long long u64;
typedef unsigned int u32;

#define LN_EPS 1e-5f

// B=32, S=256, H=1024, HL=512, E=256, L=5. All big GEMMs have K=1024.

__device__ __forceinline__ float sigmoidf_(float x) {
    return 1.f / (1.f + __expf(-x));
}
__device__ __forceinline__ float tanhf_(float x) {
    float e = __expf(-2.f * fabsf(x));
    float t = (1.f - e) / (1.f + e);
    return copysignf(t, x);
}

// ---------- f32 -> bf16 convert (vector-4) ----------
__global__ void cvt_f32_bf16(const float* __restrict__ in, bft* __restrict__ out, int n4) {
    int i = blockIdx.x * blockDim.x + threadIdx.x;
    if (i < n4) {
        float4 v = ((const float4*)in)[i];
        bf16x4 o = { (bft)v.x, (bft)v.y, (bft)v.z, (bft)v.w };
        ((bf16x4*)out)[i] = o;
    }
}

__global__ void zero_u32(u32* __restrict__ p, int n) {
    int i = blockIdx.x * blockDim.x + threadIdx.x;
    if (i < n) p[i] = 0u;
}

// ---------- transpose+convert W1/W2 ([L][K=h][N=d] f32 -> [L][N][K] bf16) ----------
__global__ __launch_bounds__(256) void transpose_cvt_w(
    const float* __restrict__ W1, const float* __restrict__ W2,
    bft* __restrict__ W1t, bft* __restrict__ W2t)
{
    __shared__ float tile[32][33];
    int z = blockIdx.z;
    int l = z >> 1;
    const float* src = ((z & 1) ? W2 : W1) + ((size_t)l << 20);
    bft* dst = ((z & 1) ? W2t : W1t) + ((size_t)l << 20);
    int tx = threadIdx.x & 31, ty = threadIdx.x >> 5;
    int bx = blockIdx.x * 32, by = blockIdx.y * 32;
    for (int r = ty; r < 32; r += 8)
        tile[r][tx] = src[(size_t)(by + r) * 1024 + bx + tx];
    __syncthreads();
    for (int r = ty; r < 32; r += 8)
        dst[(size_t)(bx + r) * 1024 + by + tx] = (bft)tile[tx][r];
}

// ---------- bf16 MFMA GEMM, 128x128 tile, BK=32, 4 waves, B^T ([N][K]) input ----------
__global__ __launch_bounds__(256) void gemm_bt(
    const bft* __restrict__ A, const bft* __restrict__ Bt,
    const float* __restrict__ bias, const int* __restrict__ langs,
    int langStrideB, int langStrideBias,
    float* __restrict__ outF, bft* __restrict__ outB,
    int remapLog, int remapMul, int ldc)
{
    const int K = 1024;
    int tn = blockIdx.x, tm = blockIdx.y;
    int row0 = tm * 128, col0 = tn * 128;
    int lang = langs ? langs[row0 >> 8] : 0;   // 256 rows per batch elem; 128-tile never crosses b
    const bft* Ap = A + (size_t)row0 * K;
    const bft* Bp = Bt + (size_t)lang * langStrideB + (size_t)col0 * K;
    const float* biasp = bias + (size_t)lang * langStrideBias + col0;

    __shared__ bft As[128 * 32];
    __shared__ bft Bs[128 * 32];

    int t = threadIdx.x;
    int lane = t & 63, wave = t >> 6;
    int wm = wave & 1, wn = wave >> 1;
    int lrow = lane & 15, quad = lane >> 4;

    f32x4 acc[4][4] = {};

    for (int k0 = 0; k0 < K; k0 += 32) {
        __syncthreads();
        for (int c = t; c < 512; c += 256) {       // 512 chunks of 8 bf16 (16B)
            int r = c >> 2, co = (c & 3) << 3;
            *(uint4*)(As + r * 32 + co) = *(const uint4*)(Ap + (size_t)r * K + k0 + co);
            *(uint4*)(Bs + r * 32 + co) = *(const uint4*)(Bp + (size_t)r * K + k0 + co);
        }
        __syncthreads();
        bf16x8 af[4], bfr[4];
#pragma unroll
        for (int i = 0; i < 4; ++i)
            af[i] = *(const bf16x8*)(As + (wm * 64 + i * 16 + lrow) * 32 + quad * 8);
#pragma unroll
        for (int j = 0; j < 4; ++j)
            bfr[j] = *(const bf16x8*)(Bs + (wn * 64 + j * 16 + lrow) * 32 + quad * 8);
#pragma unroll
        for (int i = 0; i < 4; ++i)
#pragma unroll
            for (int j = 0; j < 4; ++j)
                acc[i][j] = __builtin_amdgcn_mfma_f32_16x16x32_bf16(af[i], bfr[j], acc[i][j], 0, 0, 0);
    }

#pragma unroll
    for (int i = 0; i < 4; ++i) {
#pragma unroll
        for (int j = 0; j < 4; ++j) {
#pragma unroll
            for (int r = 0; r < 4; ++r) {
                int m = wm * 64 + i * 16 + quad * 4 + r;   // C row = quad*4+reg
                int n = wn * 64 + j * 16 + lrow;           // C col = lane&15
                int grow = row0 + m;
                int orow = remapLog ? ((grow & ((1 << remapLog) - 1)) * remapMul + (grow >> remapLog))
                                    : grow;
                float v = acc[i][j][r] + biasp[n];
                size_t idx = (size_t)orow * ldc + col0 + n;
                if (outF) outF[idx] = v;
                else outB[idx] = (bft)v;
            }
        }
    }
}

// ---------- LayerNorm + ReLU per row, f32 in -> bf16 out ----------
__global__ __launch_bounds__(256) void ln_relu_kernel(
    const float* __restrict__ h1, bft* __restrict__ a2,
    const float* __restrict__ ln_g, const float* __restrict__ ln_b,
    const int* __restrict__ langs)
{
    int row = blockIdx.x;
    int lang = langs[row >> 8];
    const float* x = h1 + (size_t)row * 1024;
    int t = threadIdx.x;
    float4 v = ((const float4*)x)[t];
    float s = v.x + v.y + v.z + v.w;
    float ss = v.x * v.x + v.y * v.y + v.z * v.z + v.w * v.w;
#pragma unroll
    for (int off = 32; off > 0; off >>= 1) {
        s += __shfl_down(s, off, 64);
        ss += __shfl_down(ss, off, 64);
    }
    __shared__ float red[8];
    int wave = t >> 6, lane = t & 63;
    if (lane == 0) { red[wave] = s; red[4 + wave] = ss; }
    __syncthreads();
    float S = red[0] + red[1] + red[2] + red[3];
    float SS = red[4] + red[5] + red[6] + red[7];
    float mean = S * (1.f / 1024.f);
    float var = SS * (1.f / 1024.f) - mean * mean;   // population var (ddof=0)
    float inv = rsqrtf(var + LN_EPS);
    float4 g = ((const float4*)(ln_g + (size_t)lang * 1024))[t];
    float4 b = ((const float4*)(ln_b + (size_t)lang * 1024))[t];
    float y0 = fmaxf(0.f, (v.x - mean) * inv * g.x + b.x);
    float y1 = fmaxf(0.f, (v.y - mean) * inv * g.y + b.y);
    float y2 = fmaxf(0.f, (v.z - mean) * inv * g.z + b.z);
    float y3 = fmaxf(0.f, (v.w - mean) * inv * g.w + b.w);
    bf16x4 o = { (bft)y0, (bft)y1, (bft)y2, (bft)y3 };
    ((bf16x4*)(a2 + (size_t)row * 1024))[t] = o;
}

// ---------- BiLSTM recurrence ----------
// 128 WGs (64/dir, 8 h-cols each). Sync is fused into the data: each h entry is a
// tagged u64 ((step_tag<<32)|bf16x2) stored with agent-scope relaxed atomics
// (LLC-coherent). Readers poll the entry tags directly — no flags, no fences,
// one LLC visibility latency per step. Directions fully decoupled.
// hgT: [dir(2)][parity(2)][32][256] u64. Parity p holds h_{it} for it with it&1==p,
// stored tag == it (prezero gives tag 0 = valid h_0 = 0).
// gin_*: [S][B][2048] bf16 (x@Wih.T + b, gate i,f,g,o). Whh_*: [2048][512] bf16.
// ys: [S][B][1024] bf16 (f|b).
__global__ __launch_bounds__(256) void bilstm_kernel(
    const bft* __restrict__ gin_f, const bft* __restrict__ gin_b,
    const bft* __restrict__ Whh_f, const bft* __restrict__ Whh_b,
    const int* __restrict__ mask, bft* __restrict__ ys, u64* __restrict__ hgT)
{
    __shared__ u64 smem[8192];                 // 64 KB
    bft* Wlds = (bft*)smem;                    // [32][512] bf16, 16B-block XOR swizzle
    bft* hs   = (bft*)(smem + 4096);           // [32][512] bf16, same swizzle
    u32* hsd  = (u32*)(smem + 4096);           // dword view of hs for staging
    float* gatesF = (float*)(smem + 4096);     // [32][33] f32, aliases hs (used after S3)

    int blk = blockIdx.x;
    int dir = blk >> 6;                 // 0 = forward, 1 = backward
    int gslice = blk & 63;
    int jbase = gslice << 3;            // this WG owns h cols [jbase, jbase+8)
    const bft* Whh = dir ? Whh_b : Whh_f;
    const bft* gin = dir ? gin_b : gin_f;

    int t = threadIdx.x;
    int lane = t & 63, wave = t >> 6;
    int wm = wave & 1, wn = wave >> 1;
    int lrow = lane & 15, quad = lane >> 4;
    int am = t >> 2, jp = t & 3;        // activation phase: t<128, 2 cols each

    // preload Whh slice into LDS (swizzled): row r (gate=r/8, j=jbase+r%8)
    for (int i = 0; i < 8; ++i) {
        int c = t + i * 256;                       // 2048 chunks of 16B: r in [0,32), b64 in [0,64)
        int r = c >> 6, b64 = c & 63;
        int gate = r >> 3, jj = r & 7;
        int phys = b64 ^ (r & 7);
        ((uint4*)Wlds)[r * 64 + phys] =
            ((const uint4*)(Whh + (size_t)(gate * 512 + jbase + jj) * 512))[b64];
    }

    float cs0 = 0.f, cs1 = 0.f, hp0 = 0.f, hp1 = 0.f;  // cell/hidden state, 2 cols/thread
    u32* ysU = (u32*)ys;

    // staging swizzle pieces (entry cp = t, row = i): dword slot within hs
    int tb = t >> 2, tl = t & 3;

    for (int it = 0; it < 256; ++it) {
        int tt = dir ? (255 - it) : it;

        // ---- prefetch gin for this step (independent of h) ----
        bf16x2 gpre[4];
        if (t < 128) {
            size_t gb = ((size_t)tt * 32 + am) * 1024 + (jbase >> 1) + jp;
#pragma unroll
            for (int g = 0; g < 4; ++g)
                gpre[g] = ((const bf16x2*)gin)[gb + g * 256];
        }
        int mk = (t < 128) ? mask[am * 256 + tt] : 0;

        // ---- stage h_prev into LDS, polling tags (h entries carry their own sync) ----
        {
            const u64* hq = hgT + (size_t)(dir * 2 + (it & 1)) * 8192 + t;
            u32 expect = (u32)it;
            u32 pend = 0;
#pragma unroll
            for (int i = 0; i < 32; ++i) {
                u64 v = __hip_atomic_load(hq + i * 256, __ATOMIC_RELAXED, __HIP_MEMORY_SCOPE_AGENT);
                if ((u32)(v >> 32) == expect)
                    hsd[i * 256 + (((tb ^ (i & 7)) << 2) | tl)] = (u32)v;
                else
                    pend |= (1u << i);
            }
            while (pend) {
#pragma unroll
                for (int i = 0; i < 32; ++i) if (pend & (1u << i)) {
                    u64 v = __hip_atomic_load(hq + i * 256, __ATOMIC_RELAXED, __HIP_MEMORY_SCOPE_AGENT);
                    if ((u32)(v >> 32) == expect) {
                        hsd[i * 256 + (((tb ^ (i & 7)) << 2) | tl)] = (u32)v;
                        pend &= ~(1u << i);
                    }
                }
            }
        }
        __syncthreads();                                           // S2

        // ---- gates_hh = h_prev @ Whh_slice^T : [32x512] @ [512x32] ----
        f32x4 acc0 = {}, acc1 = {};
        int arow = wm * 16 + lrow, brow = wn * 16 + lrow;
#pragma unroll
        for (int kk = 0; kk < 16; ++kk) {
            int b16 = kk * 4 + quad;
            bf16x8 a = *(const bf16x8*)(hs   + arow * 512 + ((b16 ^ (arow & 7)) << 3));
            bf16x8 b = *(const bf16x8*)(Wlds + brow * 512 + ((b16 ^ (brow & 7)) << 3));
            if (kk & 1) acc1 = __builtin_amdgcn_mfma_f32_16x16x32_bf16(a, b, acc1, 0, 0, 0);
            else        acc0 = __builtin_amdgcn_mfma_f32_16x16x32_bf16(a, b, acc0, 0, 0, 0);
        }
        f32x4 acc = acc0 + acc1;
        __syncthreads();                                           // S3 (hs dead; gates may alias)

#pragma unroll
        for (int r = 0; r < 4; ++r)
            gatesF[(wm * 16 + quad * 4 + r) * 33 + wn * 16 + lrow] = acc[r];
        __syncthreads();                                           // S4

        // ---- activation: threads 0..127, 2 cells each ----
        if (t < 128) {
            int l0 = 2 * jp;
            const float* gr = gatesF + am * 33;
            float xi0 = gr[l0]      + (float)gpre[0][0], xi1 = gr[l0 + 1]      + (float)gpre[0][1];
            float xf0 = gr[8 + l0]  + (float)gpre[1][0], xf1 = gr[8 + l0 + 1]  + (float)gpre[1][1];
            float xg0 = gr[16 + l0] + (float)gpre[2][0], xg1 = gr[16 + l0 + 1] + (float)gpre[2][1];
            float xo0 = gr[24 + l0] + (float)gpre[3][0], xo1 = gr[24 + l0 + 1] + (float)gpre[3][1];
            float cn0 = sigmoidf_(xf0) * cs0 + sigmoidf_(xi0) * tanhf_(xg0);
            float cn1 = sigmoidf_(xf1) * cs1 + sigmoidf_(xi1) * tanhf_(xg1);
            float hn0 = sigmoidf_(xo0) * tanhf_(cn0);
            float hn1 = sigmoidf_(xo1) * tanhf_(cn1);
            union { bf16x2 v; u32 u; } hpk, ypk;
            if (mk) {
                cs0 = cn0; cs1 = cn1; hp0 = hn0; hp1 = hn1;
                hpk.v = bf16x2{ (bft)hn0, (bft)hn1 };
                ypk.u = hpk.u;
            } else {
                hpk.v = bf16x2{ (bft)hp0, (bft)hp1 };
                ypk.u = 0u;
            }
            // ys: plain store (consumed by a later kernel)
            ysU[((size_t)tt * 32 + am) * 512 + dir * 256 + (jbase >> 1) + jp] = ypk.u;
            // h state: tagged u64 entry, agent-scope atomic store (tag = it+1)
            u64 sv = ((u64)(u32)(it + 1) << 32) | (u64)hpk.u;
            size_t hidx = (size_t)(dir * 2 + ((it + 1) & 1)) * 8192 + am * 256 + (jbase >> 1) + jp;
            __hip_atomic_store(hgT + hidx, sv, __ATOMIC_RELAXED, __HIP_MEMORY_SCOPE_AGENT);
        }
        __syncthreads();                                           // S5 (gatesF/hs reuse next iter)
    }
}

// ---------- host launcher ----------
extern "C" void kernel_launch(void* const* d_in, const int* in_sizes, int n_in,
                              void* d_out, int out_size, void* d_ws, size_t ws_size,
                              hipStream_t stream)
{
    const float* X     = (const float*)d_in[0];   // [32,256,1024]
    const int*   amask = (const int*)d_in[1];     // [32,256]
    const int*   langs = (const int*)d_in[2];     // [32]
    const float* W1    = (const float*)d_in[3];   // [5,1024,1024] (K-major)
    const float* b1    = (const float*)d_in[4];   // [5,1024]
    const float* ln_g  = (const float*)d_in[5];
    const float* ln_b  = (const float*)d_in[6];
    const float* W2    = (const float*)d_in[7];
    const float* b2    = (const float*)d_in[8];
    const float* Wih_f = (const float*)d_in[9];   // [2048,1024] = [N][K]
    const float* Whh_f = (const float*)d_in[10];  // [2048,512]
    const float* b_f   = (const float*)d_in[11];  // [2048]
    const float* Wih_b = (const float*)d_in[12];
    const float* Whh_b = (const float*)d_in[13];
    const float* b_b   = (const float*)d_in[14];
    const float* Wp    = (const float*)d_in[15];  // [256,1024] = [N][K]
    const float* bp    = (const float*)d_in[16];
    float* out = (float*)d_out;

    char* ws = (char*)d_ws;
    size_t off = 0;
    auto alloc = [&](size_t bytes) -> void* {
        void* p = ws + off;
        off += (bytes + 255) & ~(size_t)255;
        return p;
    };
    bft* Xbf   = (bft*)alloc(8192ull * 1024 * 2);
    bft* W1t   = (bft*)alloc(5ull * 1024 * 1024 * 2);
    bft* W2t   = (bft*)alloc(5ull * 1024 * 1024 * 2);
    bft* Wihf  = (bft*)alloc(2048ull * 1024 * 2);
    bft* Wihb  = (bft*)alloc(2048ull * 1024 * 2);
    bft* Whhf  = (bft*)alloc(2048ull * 512 * 2);
    bft* Whhb  = (bft*)alloc(2048ull * 512 * 2);
    bft* Wpb   = (bft*)alloc(256ull * 1024 * 2);
    float* h1  = (float*)alloc(8192ull * 1024 * 4);
    bft* a2    = (bft*)alloc(8192ull * 1024 * 2);
    bft* adapt = (bft*)alloc(8192ull * 1024 * 2);
    bft* ginf  = (bft*)alloc(256ull * 32 * 2048 * 2);
    bft* ginb  = (bft*)alloc(256ull * 32 * 2048 * 2);
    bft* ysb   = (bft*)alloc(256ull * 32 * 1024 * 2);
    u64* hgT   = (u64*)alloc(2ull * 2 * 32 * 256 * 8);   // tagged h entries, 256 KB
    (void)ws_size; (void)in_sizes; (void)n_in; (void)out_size;

    auto cvt = [&](const float* src, bft* dst, int n) {
        int n4 = n >> 2;
        hipLaunchKernelGGL(cvt_f32_bf16, dim3((n4 + 255) / 256), dim3(256), 0, stream, src, dst, n4);
    };
    cvt(X, Xbf, 8192 * 1024);
    cvt(Wih_f, Wihf, 2048 * 1024);
    cvt(Wih_b, Wihb, 2048 * 1024);
    cvt(Whh_f, Whhf, 2048 * 512);
    cvt(Whh_b, Whhb, 2048 * 512);
    cvt(Wp, Wpb, 256 * 1024);
    hipLaunchKernelGGL(zero_u32, dim3(256), dim3(256), 0, stream, (u32*)hgT, 65536);
    hipLaunchKernelGGL(transpose_cvt_w, dim3(32, 32, 10), dim3(256), 0, stream, W1, W2, W1t, W2t);

    // Adapter GEMM1: h1 = X @ W1[lang] + b1[lang]   (f32 out for LN)
    hipLaunchKernelGGL(gemm_bt, dim3(8, 64), dim3(256), 0, stream,
        Xbf, W1t, b1, langs, 1024 * 1024, 1024, h1, (bft*)nullptr, 0, 0, 1024);
    // LN + ReLU -> a2 (bf16)
    hipLaunchKernelGGL(ln_relu_kernel, dim3(8192), dim3(256), 0, stream, h1, a2, ln_g, ln_b, langs);
    // Adapter GEMM2: adapt = a2 @ W2[lang] + b2[lang]   (bf16 out)
    hipLaunchKernelGGL(gemm_bt, dim3(8, 64), dim3(256), 0, stream,
        a2, W2t, b2, langs, 1024 * 1024, 1024, (float*)nullptr, adapt, 0, 0, 1024);
    // Input gates: gin = adapt @ Wih^T + b, remap row (b*256+s) -> (s*32+b), ldc 2048
    hipLaunchKernelGGL(gemm_bt, dim3(16, 64), dim3(256), 0, stream,
        adapt, Wihf, b_f, (const int*)nullptr, 0, 0, (float*)nullptr, ginf, 8, 32, 2048);
    hipLaunchKernelGGL(gemm_bt, dim3(16, 64), dim3(256), 0, stream,
        adapt, Wihb, b_b, (const int*)nullptr, 0, 0, (float*)nullptr, ginb, 8, 32, 2048);
    // Recurrence (cooperative launch guarantees co-residency for the spin-wait)
    {
        void* args[] = { (void*)&ginf, (void*)&ginb, (void*)&Whhf, (void*)&Whhb,
                         (void*)&amask, (void*)&ysb, (void*)&hgT };
        hipLaunchCooperativeKernel((const void*)bilstm_kernel, dim3(128), dim3(256), args, 0, stream);
    }
    // Projection: out = ys @ Wp^T + bp, remap row (s*32+b) -> (b*256+s), ldc 256
    hipLaunchKernelGGL(gemm_bt, dim3(2, 64), dim3(256), 0, stream,
        ysb, Wpb, bp, (const int*)nullptr, 0, 0, out, (bft*)nullptr, 5, 256, 256);
}

// Round 5
// 1238.048 us; speedup vs baseline: 2.6013x; 2.6013x over previous
//
#include <hip/hip_runtime.h>

// ---------- types ----------
typedef __bf16 bft;
typedef bft bf16x8 __attribute__((ext_vector_type(8)));
typedef bft bf16x4 __attribute__((ext_vector_type(4)));
typedef bft bf16x2 __attribute__((ext_vector_type(2)));
typedef float f32x4 __attribute__((ext_vector_type(4)));
typedef unsigned long long u64;
typedef unsigned int u32;
typedef u32 u32x4 __attribute__((ext_vector_type(4)));

#define LN_EPS 1e-5f

// B=32, S=256, H=1024, HL=512, E=256, L=5. All big GEMMs have K=1024.

__device__ __forceinline__ float sigmoidf_(float x) {
    return 1.f / (1.f + __expf(-x));
}
__device__ __forceinline__ float tanhf_(float x) {
    float e = __expf(-2.f * fabsf(x));
    float t = (1.f - e) / (1.f + e);
    return copysignf(t, x);
}

// ---------- f32 -> bf16 convert (vector-4) ----------
__global__ void cvt_f32_bf16(const float* __restrict__ in, bft* __restrict__ out, int n4) {
    int i = blockIdx.x * blockDim.x + threadIdx.x;
    if (i < n4) {
        float4 v = ((const float4*)in)[i];
        bf16x4 o = { (bft)v.x, (bft)v.y, (bft)v.z, (bft)v.w };
        ((bf16x4*)out)[i] = o;
    }
}

__global__ void zero_u32(u32* __restrict__ p, int n) {
    int i = blockIdx.x * blockDim.x + threadIdx.x;
    if (i < n) p[i] = 0u;
}

// ---------- transpose+convert W1/W2 ([L][K=h][N=d] f32 -> [L][N][K] bf16) ----------
__global__ __launch_bounds__(256) void transpose_cvt_w(
    const float* __restrict__ W1, const float* __restrict__ W2,
    bft* __restrict__ W1t, bft* __restrict__ W2t)
{
    __shared__ float tile[32][33];
    int z = blockIdx.z;
    int l = z >> 1;
    const float* src = ((z & 1) ? W2 : W1) + ((size_t)l << 20);
    bft* dst = ((z & 1) ? W2t : W1t) + ((size_t)l << 20);
    int tx = threadIdx.x & 31, ty = threadIdx.x >> 5;
    int bx = blockIdx.x * 32, by = blockIdx.y * 32;
    for (int r = ty; r < 32; r += 8)
        tile[r][tx] = src[(size_t)(by + r) * 1024 + bx + tx];
    __syncthreads();
    for (int r = ty; r < 32; r += 8)
        dst[(size_t)(bx + r) * 1024 + by + tx] = (bft)tile[tx][r];
}

// ---------- bf16 MFMA GEMM, 128x128 tile, BK=32, 4 waves, B^T ([N][K]) input ----------
__global__ __launch_bounds__(256) void gemm_bt(
    const bft* __restrict__ A, const bft* __restrict__ Bt,
    const float* __restrict__ bias, const int* __restrict__ langs,
    int langStrideB, int langStrideBias,
    float* __restrict__ outF, bft* __restrict__ outB,
    int remapLog, int remapMul, int ldc)
{
    const int K = 1024;
    int tn = blockIdx.x, tm = blockIdx.y;
    int row0 = tm * 128, col0 = tn * 128;
    int lang = langs ? langs[row0 >> 8] : 0;   // 256 rows per batch elem; 128-tile never crosses b
    const bft* Ap = A + (size_t)row0 * K;
    const bft* Bp = Bt + (size_t)lang * langStrideB + (size_t)col0 * K;
    const float* biasp = bias + (size_t)lang * langStrideBias + col0;

    __shared__ bft As[128 * 32];
    __shared__ bft Bs[128 * 32];

    int t = threadIdx.x;
    int lane = t & 63, wave = t >> 6;
    int wm = wave & 1, wn = wave >> 1;
    int lrow = lane & 15, quad = lane >> 4;

    f32x4 acc[4][4] = {};

    for (int k0 = 0; k0 < K; k0 += 32) {
        __syncthreads();
        for (int c = t; c < 512; c += 256) {       // 512 chunks of 8 bf16 (16B)
            int r = c >> 2, co = (c & 3) << 3;
            *(uint4*)(As + r * 32 + co) = *(const uint4*)(Ap + (size_t)r * K + k0 + co);
            *(uint4*)(Bs + r * 32 + co) = *(const uint4*)(Bp + (size_t)r * K + k0 + co);
        }
        __syncthreads();
        bf16x8 af[4], bfr[4];
#pragma unroll
        for (int i = 0; i < 4; ++i)
            af[i] = *(const bf16x8*)(As + (wm * 64 + i * 16 + lrow) * 32 + quad * 8);
#pragma unroll
        for (int j = 0; j < 4; ++j)
            bfr[j] = *(const bf16x8*)(Bs + (wn * 64 + j * 16 + lrow) * 32 + quad * 8);
#pragma unroll
        for (int i = 0; i < 4; ++i)
#pragma unroll
            for (int j = 0; j < 4; ++j)
                acc[i][j] = __builtin_amdgcn_mfma_f32_16x16x32_bf16(af[i], bfr[j], acc[i][j], 0, 0, 0);
    }

#pragma unroll
    for (int i = 0; i < 4; ++i) {
#pragma unroll
        for (int j = 0; j < 4; ++j) {
#pragma unroll
            for (int r = 0; r < 4; ++r) {
                int m = wm * 64 + i * 16 + quad * 4 + r;   // C row = quad*4+reg
                int n = wn * 64 + j * 16 + lrow;           // C col = lane&15
                int grow = row0 + m;
                int orow = remapLog ? ((grow & ((1 << remapLog) - 1)) * remapMul + (grow >> remapLog))
                                    : grow;
                float v = acc[i][j][r] + biasp[n];
                size_t idx = (size_t)orow * ldc + col0 + n;
                if (outF) outF[idx] = v;
                else outB[idx] = (bft)v;
            }
        }
    }
}

// ---------- LayerNorm + ReLU per row, f32 in -> bf16 out ----------
__global__ __launch_bounds__(256) void ln_relu_kernel(
    const float* __restrict__ h1, bft* __restrict__ a2,
    const float* __restrict__ ln_g, const float* __restrict__ ln_b,
    const int* __restrict__ langs)
{
    int row = blockIdx.x;
    int lang = langs[row >> 8];
    const float* x = h1 + (size_t)row * 1024;
    int t = threadIdx.x;
    float4 v = ((const float4*)x)[t];
    float s = v.x + v.y + v.z + v.w;
    float ss = v.x * v.x + v.y * v.y + v.z * v.z + v.w * v.w;
#pragma unroll
    for (int off = 32; off > 0; off >>= 1) {
        s += __shfl_down(s, off, 64);
        ss += __shfl_down(ss, off, 64);
    }
    __shared__ float red[8];
    int wave = t >> 6, lane = t & 63;
    if (lane == 0) { red[wave] = s; red[4 + wave] = ss; }
    __syncthreads();
    float S = red[0] + red[1] + red[2] + red[3];
    float SS = red[4] + red[5] + red[6] + red[7];
    float mean = S * (1.f / 1024.f);
    float var = SS * (1.f / 1024.f) - mean * mean;   // population var (ddof=0)
    float inv = rsqrtf(var + LN_EPS);
    float4 g = ((const float4*)(ln_g + (size_t)lang * 1024))[t];
    float4 b = ((const float4*)(ln_b + (size_t)lang * 1024))[t];
    float y0 = fmaxf(0.f, (v.x - mean) * inv * g.x + b.x);
    float y1 = fmaxf(0.f, (v.y - mean) * inv * g.y + b.y);
    float y2 = fmaxf(0.f, (v.z - mean) * inv * g.z + b.z);
    float y3 = fmaxf(0.f, (v.w - mean) * inv * g.w + b.w);
    bf16x4 o = { (bft)y0, (bft)y1, (bft)y2, (bft)y3 };
    ((bf16x4*)(a2 + (size_t)row * 1024))[t] = o;
}

// ---------- BiLSTM recurrence ----------
// 128 WGs (64/dir, 8 h-cols each). Flag protocol with MINIMAL LLC transactions:
//  - producers: coalesced plain sc0+sc1 (L1/L2-bypass -> LLC) dword stores of h,
//    per-thread vmcnt(0), barrier, then ONE atomicAdd per WG into a padded sub-counter.
//  - consumers: 8 poller lanes read 8 padded sub-counters (8 loads/WG/poll round),
//    then stage 32 KB h via 8 fully-coalesced global_load_dwordx4 sc0 sc1.
// hg: [dir(2)][parity(2)][32][256] u32 (bf16x2 entries). ctr: [dir][256][8 x 64B-padded].
// gin_*: [S][B][2048] bf16 (x@Wih.T + b, gate i,f,g,o). Whh_*: [2048][512] bf16.
// ys: [S][B][1024] bf16 (f|b), stored AFTER the counter bump (off critical path).
__global__ __launch_bounds__(256) void bilstm_kernel(
    const bft* __restrict__ gin_f, const bft* __restrict__ gin_b,
    const bft* __restrict__ Whh_f, const bft* __restrict__ Whh_b,
    const int* __restrict__ mask, bft* __restrict__ ys,
    u32* __restrict__ hg, u32* __restrict__ ctr)
{
    __shared__ u64 smem[8192];                 // 64 KB
    bft* Wlds = (bft*)smem;                    // [32][512] bf16, 16B-block XOR swizzle
    bft* hs   = (bft*)(smem + 4096);           // [32][512] bf16, same swizzle
    u32* hsd  = (u32*)(smem + 4096);           // dword view of hs for staging
    float* gatesF = (float*)(smem + 4096);     // [32][33] f32, aliases hs (used after S3)

    int blk = blockIdx.x;
    int dir = blk >> 6;                 // 0 = forward, 1 = backward
    int gslice = blk & 63;
    int jbase = gslice << 3;            // this WG owns h cols [jbase, jbase+8)
    const bft* Whh = dir ? Whh_b : Whh_f;
    const bft* gin = dir ? gin_b : gin_f;

    int t = threadIdx.x;
    int lane = t & 63, wave = t >> 6;
    int wm = wave & 1, wn = wave >> 1;
    int lrow = lane & 15, quad = lane >> 4;
    int am = t >> 2, jp = t & 3;        // activation phase: t<128, 2 cols each

    // preload Whh slice into LDS (swizzled): row r (gate=r/8, j=jbase+r%8)
    for (int i = 0; i < 8; ++i) {
        int c = t + i * 256;                       // 2048 chunks of 16B: r in [0,32), b64 in [0,64)
        int r = c >> 6, b64 = c & 63;
        int gate = r >> 3, jj = r & 7;
        int phys = b64 ^ (r & 7);
        ((uint4*)Wlds)[r * 64 + phys] =
            ((const uint4*)(Whh + (size_t)(gate * 512 + jbase + jj) * 512))[b64];
    }

    float cs0 = 0.f, cs1 = 0.f, hp0 = 0.f, hp1 = 0.f;  // cell/hidden state, 2 cols/thread
    u32* ysU = (u32*)ys;
    int mloS = t >> 6;                  // staging: within load i, row m = i*4 + (t>>6)
    int b16S = t & 63;                  // staging: 16B-block index within row

    for (int it = 0; it < 256; ++it) {
        int tt = dir ? (255 - it) : it;

        // ---- prefetch gin + mask for this step (independent of h) ----
        bf16x2 gpre[4];
        int mk = 0;
        if (t < 128) {
            size_t gb = ((size_t)tt * 32 + am) * 1024 + (jbase >> 1) + jp;
#pragma unroll
            for (int g = 0; g < 4; ++g)
                gpre[g] = ((const bf16x2*)gin)[gb + g * 256];
            mk = mask[am * 256 + tt];
        }

        // ---- wait + stage h_prev into LDS (swizzled) ----
        if (it == 0) {
#pragma unroll
            for (int i = 0; i < 16; ++i)
                smem[4096 + t + i * 256] = 0ull;
        } else {
            if (wave == 0) {
                const u32* cp = ctr + (size_t)(dir * 256 + it) * 128 + (lane < 8 ? lane * 16 : 0);
                for (;;) {
                    u32 c = 8u;
                    if (lane < 8)
                        c = __hip_atomic_load(cp, __ATOMIC_RELAXED, __HIP_MEMORY_SCOPE_AGENT);
                    if (__all(c >= 8u)) break;
                    __builtin_amdgcn_s_sleep(2);
                }
            }
            __syncthreads();                                       // S1
            const u32* hq = hg + (size_t)(dir * 2 + (it & 1)) * 8192;
            u32x4 r[8];
#pragma unroll
            for (int i = 0; i < 8; ++i)
                asm volatile("global_load_dwordx4 %0, %1, off sc0 sc1"
                             : "=v"(r[i]) : "v"(hq + i * 1024 + t * 4) : "memory");
            asm volatile("s_waitcnt vmcnt(0)" ::: "memory");
#pragma unroll
            for (int i = 0; i < 8; ++i) {
                int m = i * 4 + mloS;
                *(u32x4*)(hsd + m * 256 + ((b16S ^ (m & 7)) << 2)) = r[i];
            }
        }
        __syncthreads();                                           // S2

        // ---- gates_hh = h_prev @ Whh_slice^T : [32x512] @ [512x32] ----
        f32x4 acc0 = {}, acc1 = {};
        int arow = wm * 16 + lrow, brow = wn * 16 + lrow;
#pragma unroll
        for (int kk = 0; kk < 16; ++kk) {
            int b16 = kk * 4 + quad;
            bf16x8 a = *(const bf16x8*)(hs   + arow * 512 + ((b16 ^ (arow & 7)) << 3));
            bf16x8 b = *(const bf16x8*)(Wlds + brow * 512 + ((b16 ^ (brow & 7)) << 3));
            if (kk & 1) acc1 = __builtin_amdgcn_mfma_f32_16x16x32_bf16(a, b, acc1, 0, 0, 0);
            else        acc0 = __builtin_amdgcn_mfma_f32_16x16x32_bf16(a, b, acc0, 0, 0, 0);
        }
        f32x4 acc = acc0 + acc1;
        __syncthreads();                                           // S3 (hs dead; gates may alias)

#pragma unroll
        for (int r = 0; r < 4; ++r)
            gatesF[(wm * 16 + quad * 4 + r) * 33 + wn * 16 + lrow] = acc[r];
        __syncthreads();                                           // S4

        // ---- activation: threads 0..127, 2 cells each ----
        u32 ypack = 0;
        if (t < 128) {
            int l0 = 2 * jp;
            const float* gr = gatesF + am * 33;
            float xi0 = gr[l0]      + (float)gpre[0][0], xi1 = gr[l0 + 1]      + (float)gpre[0][1];
            float xf0 = gr[8 + l0]  + (float)gpre[1][0], xf1 = gr[8 + l0 + 1]  + (float)gpre[1][1];
            float xg0 = gr[16 + l0] + (float)gpre[2][0], xg1 = gr[16 + l0 + 1] + (float)gpre[2][1];
            float xo0 = gr[24 + l0] + (float)gpre[3][0], xo1 = gr[24 + l0 + 1] + (float)gpre[3][1];
            float cn0 = sigmoidf_(xf0) * cs0 + sigmoidf_(xi0) * tanhf_(xg0);
            float cn1 = sigmoidf_(xf1) * cs1 + sigmoidf_(xi1) * tanhf_(xg1);
            float hn0 = sigmoidf_(xo0) * tanhf_(cn0);
            float hn1 = sigmoidf_(xo1) * tanhf_(cn1);
            union { bf16x2 v; u32 u; } hpk, ypk;
            if (mk) {
                cs0 = cn0; cs1 = cn1; hp0 = hn0; hp1 = hn1;
                hpk.v = bf16x2{ (bft)hn0, (bft)hn1 };
                ypk.u = hpk.u;
            } else {
                hpk.v = bf16x2{ (bft)hp0, (bft)hp1 };
                ypk.u = 0u;
            }
            ypack = ypk.u;
            // h store: plain coalescing store, L1/L2-bypass -> LLC
            u32* ha = hg + (size_t)(dir * 2 + ((it + 1) & 1)) * 8192 + am * 256 + gslice * 4 + jp;
            u32 hv = hpk.u;
            asm volatile("global_store_dword %0, %1, off sc0 sc1" :: "v"(ha), "v"(hv) : "memory");
        }
        asm volatile("s_waitcnt vmcnt(0)" ::: "memory");           // own stores acked at LLC
        __syncthreads();                                           // S5
        if (t == 0 && it < 255)
            __hip_atomic_fetch_add(ctr + (size_t)(dir * 256 + it + 1) * 128 + (gslice & 7) * 16,
                                   1u, __ATOMIC_RELAXED, __HIP_MEMORY_SCOPE_AGENT);
        // ys store AFTER the signal — off the critical path
        if (t < 128)
            ysU[((size_t)tt * 32 + am) * 512 + dir * 256 + gslice * 4 + jp] = ypack;
    }
}

// ---------- host launcher ----------
extern "C" void kernel_launch(void* const* d_in, const int* in_sizes, int n_in,
                              void* d_out, int out_size, void* d_ws, size_t ws_size,
                              hipStream_t stream)
{
    const float* X     = (const float*)d_in[0];   // [32,256,1024]
    const int*   amask = (const int*)d_in[1];     // [32,256]
    const int*   langs = (const int*)d_in[2];     // [32]
    const float* W1    = (const float*)d_in[3];   // [5,1024,1024] (K-major)
    const float* b1    = (const float*)d_in[4];   // [5,1024]
    const float* ln_g  = (const float*)d_in[5];
    const float* ln_b  = (const float*)d_in[6];
    const float* W2    = (const float*)d_in[7];
    const float* b2    = (const float*)d_in[8];
    const float* Wih_f = (const float*)d_in[9];   // [2048,1024] = [N][K]
    const float* Whh_f = (const float*)d_in[10];  // [2048,512]
    const float* b_f   = (const float*)d_in[11];  // [2048]
    const float* Wih_b = (const float*)d_in[12];
    const float* Whh_b = (const float*)d_in[13];
    const float* b_b   = (const float*)d_in[14];
    const float* Wp    = (const float*)d_in[15];  // [256,1024] = [N][K]
    const float* bp    = (const float*)d_in[16];
    float* out = (float*)d_out;

    char* ws = (char*)d_ws;
    size_t off = 0;
    auto alloc = [&](size_t bytes) -> void* {
        void* p = ws + off;
        off += (bytes + 255) & ~(size_t)255;
        return p;
    };
    bft* Xbf   = (bft*)alloc(8192ull * 1024 * 2);
    bft* W1t   = (bft*)alloc(5ull * 1024 * 1024 * 2);
    bft* W2t   = (bft*)alloc(5ull * 1024 * 1024 * 2);
    bft* Wihf  = (bft*)alloc(2048ull * 1024 * 2);
    bft* Wihb  = (bft*)alloc(2048ull * 1024 * 2);
    bft* Whhf  = (bft*)alloc(2048ull * 512 * 2);
    bft* Whhb  = (bft*)alloc(2048ull * 512 * 2);
    bft* Wpb   = (bft*)alloc(256ull * 1024 * 2);
    float* h1  = (float*)alloc(8192ull * 1024 * 4);
    bft* a2    = (bft*)alloc(8192ull * 1024 * 2);
    bft* adapt = (bft*)alloc(8192ull * 1024 * 2);
    bft* ginf  = (bft*)alloc(256ull * 32 * 2048 * 2);
    bft* ginb  = (bft*)alloc(256ull * 32 * 2048 * 2);
    bft* ysb   = (bft*)alloc(256ull * 32 * 1024 * 2);
    u32* hg    = (u32*)alloc(2ull * 2 * 32 * 256 * 4);   // h entries (bf16x2), 256 KB
    u32* ctr   = (u32*)alloc(2ull * 256 * 8 * 16 * 4);   // padded step counters, 256 KB
    (void)ws_size; (void)in_sizes; (void)n_in; (void)out_size;

    auto cvt = [&](const float* src, bft* dst, int n) {
        int n4 = n >> 2;
        hipLaunchKernelGGL(cvt_f32_bf16, dim3((n4 + 255) / 256), dim3(256), 0, stream, src, dst, n4);
    };
    cvt(X, Xbf, 8192 * 1024);
    cvt(Wih_f, Wihf, 2048 * 1024);
    cvt(Wih_b, Wihb, 2048 * 1024);
    cvt(Whh_f, Whhf, 2048 * 512);
    cvt(Whh_b, Whhb, 2048 * 512);
    cvt(Wp, Wpb, 256 * 1024);
    hipLaunchKernelGGL(zero_u32, dim3(256), dim3(256), 0, stream, ctr, 65536);
    hipLaunchKernelGGL(transpose_cvt_w, dim3(32, 32, 10), dim3(256), 0, stream, W1, W2, W1t, W2t);

    // Adapter GEMM1: h1 = X @ W1[lang] + b1[lang]   (f32 out for LN)
    hipLaunchKernelGGL(gemm_bt, dim3(8, 64), dim3(256), 0, stream,
        Xbf, W1t, b1, langs, 1024 * 1024, 1024, h1, (bft*)nullptr, 0, 0, 1024);
    // LN + ReLU -> a2 (bf16)
    hipLaunchKernelGGL(ln_relu_kernel, dim3(8192), dim3(256), 0, stream, h1, a2, ln_g, ln_b, langs);
    // Adapter GEMM2: adapt = a2 @ W2[lang] + b2[lang]   (bf16 out)
    hipLaunchKernelGGL(gemm_bt, dim3(8, 64), dim3(256), 0, stream,
        a2, W2t, b2, langs, 1024 * 1024, 1024, (float*)nullptr, adapt, 0, 0, 1024);
    // Input gates: gin = adapt @ Wih^T + b, remap row (b*256+s) -> (s*32+b), ldc 2048
    hipLaunchKernelGGL(gemm_bt, dim3(16, 64), dim3(256), 0, stream,
        adapt, Wihf, b_f, (const int*)nullptr, 0, 0, (float*)nullptr, ginf, 8, 32, 2048);
    hipLaunchKernelGGL(gemm_bt, dim3(16, 64), dim3(256), 0, stream,
        adapt, Wihb, b_b, (const int*)nullptr, 0, 0, (float*)nullptr, ginb, 8, 32, 2048);
    // Recurrence (cooperative launch guarantees co-residency for the spin-wait)
    {
        void* args[] = { (void*)&ginf, (void*)&ginb, (void*)&Whhf, (void*)&Whhb,
                         (void*)&amask, (void*)&ysb, (void*)&hg, (void*)&ctr };
        hipLaunchCooperativeKernel((const void*)bilstm_kernel, dim3(128), dim3(256), args, 0, stream);
    }
    // Projection: out = ys @ Wp^T + bp, remap row (s*32+b) -> (b*256+s), ldc 256
    hipLaunchKernelGGL(gemm_bt, dim3(2, 64), dim3(256), 0, stream,
        ysb, Wpb, bp, (const int*)nullptr, 0, 0, out, (bft*)nullptr, 5, 256, 256);
}